// Round 2
// baseline (20.663 us; speedup 1.0000x reference)
//
#include <hip/hip_runtime.h>
#include <hip/hip_bf16.h>

// SoftToHardQuantize forward:
//   out = stop_gradient(hard - y) + y  ==  hard  (soft path cancels in value).
// Must bit-match np.argmin(|x - C[l]|) over l in ORIGINAL order (first
// occurrence wins ties), computed in fp32 — so do the exact 16-way scan,
// no sorted-midpoint shortcut (it disagrees in a ~1-ulp window at cell
// boundaries; R1 absmax 0.125 came from exactly that).

#define NCODES 16

__global__ __launch_bounds__(256) void stq_main(const float4* __restrict__ in,
                                                float4* __restrict__ out,
                                                const float* __restrict__ C,
                                                int n4,
                                                const float* __restrict__ in_tail,
                                                float* __restrict__ out_tail,
                                                int n_tail) {
    // Uniform codebook -> scalar loads -> SGPRs (compile-time indices).
    float c[NCODES];
#pragma unroll
    for (int l = 0; l < NCODES; ++l) c[l] = C[l];

    int i = blockIdx.x * blockDim.x + threadIdx.x;
    const int stride = gridDim.x * blockDim.x;

    for (; i < n4; i += stride) {
        float4 v = in[i];
        float x0 = v.x, x1 = v.y, x2 = v.z, x3 = v.w;

        float b0 = fabsf(x0 - c[0]), b1 = fabsf(x1 - c[0]);
        float b2 = fabsf(x2 - c[0]), b3 = fabsf(x3 - c[0]);
        float q0 = c[0], q1 = c[0], q2 = c[0], q3 = c[0];

#pragma unroll
        for (int l = 1; l < NCODES; ++l) {
            float cl = c[l];
            float d0 = fabsf(x0 - cl);
            float d1 = fabsf(x1 - cl);
            float d2 = fabsf(x2 - cl);
            float d3 = fabsf(x3 - cl);
            // strict < : first occurrence of the minimum wins (np.argmin)
            if (d0 < b0) { b0 = d0; q0 = cl; }
            if (d1 < b1) { b1 = d1; q1 = cl; }
            if (d2 < b2) { b2 = d2; q2 = cl; }
            if (d3 < b3) { b3 = d3; q3 = cl; }
        }

        float4 r; r.x = q0; r.y = q1; r.z = q2; r.w = q3;
        out[i] = r;
    }

    // scalar tail (n not divisible by 4)
    int t = blockIdx.x * blockDim.x + threadIdx.x;
    if (t < n_tail) {
        float x = in_tail[t];
        float b = fabsf(x - c[0]);
        float q = c[0];
#pragma unroll
        for (int l = 1; l < NCODES; ++l) {
            float d = fabsf(x - c[l]);
            if (d < b) { b = d; q = c[l]; }
        }
        out_tail[t] = q;
    }
}

extern "C" void kernel_launch(void* const* d_in, const int* in_sizes, int n_in,
                              void* d_out, int out_size, void* d_ws, size_t ws_size,
                              hipStream_t stream) {
    const float* inp = (const float*)d_in[0];
    const float* C   = (const float*)d_in[1];
    // d_in[2] = sigma: unused (forward value is exactly the hard quantize)
    float* out = (float*)d_out;

    const int n = in_sizes[0];

    const int n4 = n / 4;
    const int n_tail = n - n4 * 4;
    int blocks = (n4 + 255) / 256;
    if (blocks > 2048) blocks = 2048;
    if (blocks < 1) blocks = 1;

    stq_main<<<blocks, 256, 0, stream>>>((const float4*)inp, (float4*)out, C, n4,
                                         inp + n4 * 4, out + n4 * 4, n_tail);
}

// Round 4
// 18.681 us; speedup vs baseline: 1.1061x; 1.1061x over previous
//
#include <hip/hip_runtime.h>
#include <hip/hip_bf16.h>

// SoftToHardQuantize forward == hard quantize (soft path cancels in value).
// Exact np.argmin(|x - C[l]|) semantics: scan in original order, strict <,
// all fp32 (R1 showed any surrogate comparison breaks at 1-ulp boundaries).
//
// R3: 4x unroll, all 4 dwordx4 loads issued before compute (R2 had 1 load in
// flight/wave -> no mem/VALU overlap: 20.7us vs 10.2us roofline).
// R4 fix: __builtin_nontemporal_store needs a NATIVE vector type, not
// HIP_vector_type -> use ext_vector_type(4) float throughout.

#define NCODES 16

typedef float vfloat4 __attribute__((ext_vector_type(4)));

__device__ __forceinline__ vfloat4 quant4(vfloat4 v, const float* c) {
    float x0 = v.x, x1 = v.y, x2 = v.z, x3 = v.w;
    float b0 = fabsf(x0 - c[0]), b1 = fabsf(x1 - c[0]);
    float b2 = fabsf(x2 - c[0]), b3 = fabsf(x3 - c[0]);
    float q0 = c[0], q1 = c[0], q2 = c[0], q3 = c[0];
#pragma unroll
    for (int l = 1; l < NCODES; ++l) {
        float cl = c[l];
        float d0 = fabsf(x0 - cl);
        float d1 = fabsf(x1 - cl);
        float d2 = fabsf(x2 - cl);
        float d3 = fabsf(x3 - cl);
        if (d0 < b0) { b0 = d0; q0 = cl; }  // strict <: first min wins (np.argmin)
        if (d1 < b1) { b1 = d1; q1 = cl; }
        if (d2 < b2) { b2 = d2; q2 = cl; }
        if (d3 < b3) { b3 = d3; q3 = cl; }
    }
    vfloat4 r;
    r.x = q0; r.y = q1; r.z = q2; r.w = q3;
    return r;
}

__global__ __launch_bounds__(256) void stq_main(const vfloat4* __restrict__ in,
                                                vfloat4* __restrict__ out,
                                                const float* __restrict__ C,
                                                int n4,
                                                const float* __restrict__ in_tail,
                                                float* __restrict__ out_tail,
                                                int n_tail) {
    // Uniform codebook -> SGPRs
    float c[NCODES];
#pragma unroll
    for (int l = 0; l < NCODES; ++l) c[l] = C[l];

    const int stride = gridDim.x * blockDim.x;
    int i = blockIdx.x * blockDim.x + threadIdx.x;

    // 4-deep: issue all 4 loads before any compute (64B/thread in flight)
    for (; i + 3 * stride < n4; i += 4 * stride) {
        vfloat4 v0 = in[i];
        vfloat4 v1 = in[i + stride];
        vfloat4 v2 = in[i + 2 * stride];
        vfloat4 v3 = in[i + 3 * stride];
        vfloat4 r0 = quant4(v0, c);
        vfloat4 r1 = quant4(v1, c);
        vfloat4 r2 = quant4(v2, c);
        vfloat4 r3 = quant4(v3, c);
        __builtin_nontemporal_store(r0, &out[i]);
        __builtin_nontemporal_store(r1, &out[i + stride]);
        __builtin_nontemporal_store(r2, &out[i + 2 * stride]);
        __builtin_nontemporal_store(r3, &out[i + 3 * stride]);
    }
    // remainder float4s
    for (; i < n4; i += stride) {
        vfloat4 r = quant4(in[i], c);
        __builtin_nontemporal_store(r, &out[i]);
    }

    // scalar tail (n not divisible by 4)
    int t = blockIdx.x * blockDim.x + threadIdx.x;
    if (t < n_tail) {
        float x = in_tail[t];
        float b = fabsf(x - c[0]);
        float q = c[0];
#pragma unroll
        for (int l = 1; l < NCODES; ++l) {
            float d = fabsf(x - c[l]);
            if (d < b) { b = d; q = c[l]; }
        }
        out_tail[t] = q;
    }
}

extern "C" void kernel_launch(void* const* d_in, const int* in_sizes, int n_in,
                              void* d_out, int out_size, void* d_ws, size_t ws_size,
                              hipStream_t stream) {
    const float* inp = (const float*)d_in[0];
    const float* C   = (const float*)d_in[1];
    // d_in[2] = sigma: unused (forward value is exactly the hard quantize)
    float* out = (float*)d_out;

    const int n = in_sizes[0];
    const int n4 = n / 4;
    const int n_tail = n - n4 * 4;

    int blocks = (n4 + 255) / 256;
    if (blocks > 2048) blocks = 2048;
    if (blocks < 1) blocks = 1;

    stq_main<<<blocks, 256, 0, stream>>>((const vfloat4*)inp, (vfloat4*)out, C, n4,
                                         inp + n4 * 4, out + n4 * 4, n_tail);
}